// Round 2
// baseline (289.208 us; speedup 1.0000x reference)
//
#include <hip/hip_runtime.h>
#include <hip/hip_bf16.h>

#define IN_F 512
#define OUT_F 512
#define LATD 512
#define RES 64
#define BATCH 8
#define EPSV 1e-8f

static constexpr float C_LIN  = 0.04419417382415922f;   // 1/sqrt(512)
static constexpr float C_CONV = 0.014731391274719739f;  // 1/sqrt(512*9)

typedef __attribute__((ext_vector_type(8)))  short short8;
typedef __attribute__((ext_vector_type(16))) float f32x16;

union BF { __hip_bfloat16 h; short s; };

__device__ __forceinline__ void async_load16(const char* g, char* l) {
  __builtin_amdgcn_global_load_lds(
      (const __attribute__((address_space(1))) unsigned int*)g,
      (__attribute__((address_space(3))) unsigned int*)l, 16, 0, 0);
}

// ---------------- s = latent @ (w_lin*C).T + b_lin ----------------
__global__ void k_compute_s(const float* __restrict__ latent,
                            const float* __restrict__ w_lin,
                            const float* __restrict__ b_lin,
                            float* __restrict__ s) {
  const int i = blockIdx.x;
  const int lane = threadIdx.x;
  const float4* wl = (const float4*)(w_lin + (size_t)i * LATD);
  const float4 w0 = wl[lane * 2], w1 = wl[lane * 2 + 1];
  float acc[BATCH];
#pragma unroll
  for (int b = 0; b < BATCH; ++b) {
    const float4* lt = (const float4*)(latent + (size_t)b * LATD);
    const float4 l0 = lt[lane * 2], l1 = lt[lane * 2 + 1];
    acc[b] = w0.x * l0.x + w0.y * l0.y + w0.z * l0.z + w0.w * l0.w +
             w1.x * l1.x + w1.y * l1.y + w1.z * l1.z + w1.w * l1.w;
  }
#pragma unroll
  for (int b = 0; b < BATCH; ++b) {
    float v = acc[b];
#pragma unroll
    for (int off = 32; off > 0; off >>= 1) v += __shfl_down(v, off);
    if (lane == 0) s[b * IN_F + i] = v * C_LIN + b_lin[i];
  }
}

// ---- wb layout: [(c*4+ob)][tap][half][o128][8ch] bf16 (16B lane-stride)
// ---- w2[o][i] = sum_t w^2 ; blocks 0..255 also zero halo borders of xmp ----
__global__ void k_prep_w(const float* __restrict__ w_conv,
                         short* __restrict__ wb,
                         float* __restrict__ w2,
                         char* __restrict__ xmp) {
  const int t = blockIdx.x * 256 + threadIdx.x;   // 262144: o*512 + i
  const int o = t >> 9;
  const int i = t & 511;
  const float* src = w_conv + (size_t)t * 9;
  const int c = i >> 4, hf0 = (i >> 3) & 1, ch = i & 7;
  const int ob = o >> 7, ol = o & 127;
  short* dst = wb + (size_t)(c * 4 + ob) * 18432 + hf0 * 1024 + ol * 8 + ch;
  float sum = 0.f;
#pragma unroll
  for (int tap = 0; tap < 9; ++tap) {
    const float v = src[tap] * C_CONV;
    sum += v * v;
    BF cv; cv.h = __float2bfloat16(v);
    dst[tap * 2048] = cv.s;
  }
  w2[t] = sum;

  // fold in halo-border zeroing (was a separate kernel): plane layout [66][2][66][16B]
  if (blockIdx.x < 256) {
    char* base = xmp + (size_t)blockIdx.x * 139392;
    for (int q = threadIdx.x; q < 520; q += 256) {
      int h, hf, w;
      if (q < 132)      { h = 0;  hf = (q >= 66) ? 1 : 0; w = q - hf * 66; }
      else if (q < 264) { const int r = q - 132; h = 65; hf = (r >= 66) ? 1 : 0; w = r - hf * 66; }
      else              { const int r = q - 264; h = (r >> 2) + 1; hf = (r >> 1) & 1; w = (r & 1) * 65; }
      *(uint4*)(base + ((size_t)(h * 132 + hf * 66 + w)) * 16) = make_uint4(0u, 0u, 0u, 0u);
    }
  }
}

// ---- sigma_inv[b][o] = rsqrt(sum_i w2[o][i]*s[b][i]^2 + eps) ----
__global__ void k_sigma(const float* __restrict__ w2,
                        const float* __restrict__ s,
                        float* __restrict__ sigma_inv) {
  const int o = blockIdx.x * 4 + (threadIdx.x >> 6);
  const int lane = threadIdx.x & 63;
  float acc[BATCH];
#pragma unroll
  for (int b = 0; b < BATCH; ++b) acc[b] = 0.f;
#pragma unroll
  for (int k = 0; k < 8; ++k) {
    const int i = k * 64 + lane;
    const float w = w2[o * IN_F + i];
#pragma unroll
    for (int b = 0; b < BATCH; ++b) {
      const float sv = s[b * IN_F + i];
      acc[b] += w * sv * sv;
    }
  }
#pragma unroll
  for (int b = 0; b < BATCH; ++b) {
    float v = acc[b];
#pragma unroll
    for (int off = 32; off > 0; off >>= 1) v += __shfl_down(v, off);
    if (lane == 0) sigma_inv[b * OUT_F + o] = rsqrtf(v + EPSV);
  }
}

// ---- xmp[(c*8+b)][h+1][half][w+1][8ch] = bf16(x[b][i][h][w] * s[b][i]) ----
__global__ void k_modulate(const float* __restrict__ x,
                           const float* __restrict__ s,
                           char* __restrict__ xmp) {
  const int h    = blockIdx.x & 63;
  const int ic32 = (blockIdx.x >> 6) & 15;
  const int b    = blockIdx.x >> 10;
  __shared__ float tile[32][65];
  const int tid = threadIdx.x;
  {
    const int il = tid >> 3, w8 = (tid & 7) * 8;
    const int i = ic32 * 32 + il;
    const float sv = s[b * IN_F + i];
    const float* xp = x + (((size_t)(b * IN_F + i) * RES + h) * RES + w8);
    const float4 v0 = *(const float4*)xp;
    const float4 v1 = *(const float4*)(xp + 4);
    tile[il][w8 + 0] = v0.x * sv; tile[il][w8 + 1] = v0.y * sv;
    tile[il][w8 + 2] = v0.z * sv; tile[il][w8 + 3] = v0.w * sv;
    tile[il][w8 + 4] = v1.x * sv; tile[il][w8 + 5] = v1.y * sv;
    tile[il][w8 + 6] = v1.z * sv; tile[il][w8 + 7] = v1.w * sv;
  }
  __syncthreads();
  {
    const int w = tid >> 2, part = tid & 3;
    const int chalf = part >> 1, hf = part & 1;
    short8 pk;
#pragma unroll
    for (int j = 0; j < 8; ++j) {
      BF cv; cv.h = __float2bfloat16(tile[chalf * 16 + hf * 8 + j][w]);
      pk[j] = cv.s;
    }
    const int c = ic32 * 2 + chalf;
    char* dst = xmp + (size_t)(c * 8 + b) * 139392 +
                ((size_t)(h + 1) * 132 + hf * 66 + (w + 1)) * 16;
    *(short8*)dst = pk;
  }
}

// ---------------- main implicit-GEMM conv ----------------
// Block: 128 o x (8 rows x 64 cols) px, 4 waves; wave = 128 o x 2 rows.
// A (weights) loaded global->VGPR (ring buffer, 2 tap-groups ahead) -> no LDS traffic.
// B (pixels) from LDS, dw-major loop dedups row reads: 24 ds_read_b128/chunk/wave.
// Per-CU per chunk: LDS ~98 KB (~770 cyc) < MFMA 1152 cyc -> MFMA-bound.
// Grid 256 = 1 block/CU. XCD = blk&7 -> ob = xcd>>1: w slice 1.18 MB L2-resident.
__global__ __launch_bounds__(256, 1)
void k_conv(const char* __restrict__ xmp,
            const short* __restrict__ wbg,
            const float* __restrict__ sigma_inv,
            const float* __restrict__ b_conv,
            float* __restrict__ out) {
  __shared__ __align__(16) char lds[42240];  // x double buffer only (2 x 21120)
  const int l = blockIdx.x;
  const int xcd = l & 7;
  const int idx = l >> 3;            // 0..31 within XCD
  const int ob = xcd >> 1;           // each ob owned by 2 XCDs
  const int b  = (xcd & 1) * 4 + (idx & 3);
  const int h0 = (idx >> 2) * 8;
  const int o0 = ob * 128;
  const int tid = threadIdx.x;
  const int wave = tid >> 6, lane = tid & 63;
  const int l31 = lane & 31, half = lane >> 5;

  f32x16 acc[4][4];
#pragma unroll
  for (int i = 0; i < 4; ++i)
#pragma unroll
    for (int j = 0; j < 4; ++j)
#pragma unroll
      for (int r = 0; r < 16; ++r) acc[i][j][r] = 0.f;

  const char* xsrc0 = xmp + (size_t)b * 139392 + (size_t)h0 * 2112;  // + ic*8*139392
  // per-lane weight base: [(ic*4+ob)][tap][half][o128][8ch]
  const char* wlane = (const char*)wbg + (size_t)ob * 36864 + half * 2048 + l31 * 16;

  // tap-group g (dw-major): dw = g/3, dh = g%3, tap = dh*3 + dw
  // A ring buffer: group j uses abuf[j%3]; prefetch for j+2 into abuf[(j+2)%3]
  short8 abuf[3][4];

  // stage chunk 0 into parity 0
#pragma unroll
  for (int k = 0; k < 5; ++k) {
    const int j = tid + k * 256;
    async_load16(xsrc0 + j * 16, lds + j * 16);
  }
  if (tid < 40) { const int j = 1280 + tid; async_load16(xsrc0 + j * 16, lds + j * 16); }
  // prologue A: chunk 0, groups 0 (tap 0) and 1 (tap 3)
#pragma unroll
  for (int f = 0; f < 4; ++f)
    abuf[0][f] = *(const short8*)(wlane + 0 * 4096 + f * 512);
#pragma unroll
  for (int f = 0; f < 4; ++f)
    abuf[1][f] = *(const short8*)(wlane + 3 * 4096 + f * 512);
  __syncthreads();

  for (int ic = 0; ic < 32; ++ic) {
    const int p = ic & 1;
    if (ic + 1 < 32) {     // prefetch next x chunk into parity p^1
      const char* xs = xsrc0 + (size_t)(ic + 1) * (8 * 139392);
      char* xd = lds + (p ^ 1) * 21120;
#pragma unroll
      for (int k = 0; k < 5; ++k) {
        const int j = tid + k * 256;
        async_load16(xs + j * 16, xd + j * 16);
      }
      if (tid < 40) { const int j = 1280 + tid; async_load16(xs + j * 16, xd + j * 16); }
    }
    const char* xp = lds + p * 21120;
#pragma unroll
    for (int dw = 0; dw < 3; ++dw) {
      // B: rows 0..3 (output rows 0,1 x taps dh 0..2 dedup'd), cols tpc*32+dw
      short8 brow[4][2];
#pragma unroll
      for (int r = 0; r < 4; ++r)
#pragma unroll
        for (int tpc = 0; tpc < 2; ++tpc)
          brow[r][tpc] = *(const short8*)(
              xp + (((wave * 2 + r) * 132) + half * 66 + tpc * 32 + dw + l31) * 16);
#pragma unroll
      for (int dh = 0; dh < 3; ++dh) {
        const int j = dw * 3 + dh;
        const int cur = j % 3;
        // prefetch A for group j+2 (possibly next chunk)
        {
          const int jn = j + 2;
          const int tgt = jn % 3;
          const int gn = (jn <= 8) ? jn : jn - 9;
          const int cn = (jn <= 8) ? ic : (ic + 1 < 32 ? ic + 1 : 31);
          const int tapn = (gn % 3) * 3 + gn / 3;
#pragma unroll
          for (int f = 0; f < 4; ++f)
            abuf[tgt][f] = *(const short8*)(
                wlane + (size_t)cn * 147456 + tapn * 4096 + f * 512);
        }
#pragma unroll
        for (int tpr = 0; tpr < 2; ++tpr)
#pragma unroll
          for (int tpc = 0; tpc < 2; ++tpc)
#pragma unroll
            for (int f = 0; f < 4; ++f)
              acc[f][tpr * 2 + tpc] = __builtin_amdgcn_mfma_f32_32x32x16_bf16(
                  abuf[cur][f], brow[dh + tpr][tpc], acc[f][tpr * 2 + tpc], 0, 0, 0);
      }
    }
    __syncthreads();
  }

  // epilogue: C/D col(lane&31) = px-within-32, row = o_local
  // o = o0 + f*32 + (reg&3) + 8*(reg>>2) + 4*half ; px: h = h0+wave*2+tpr, w = tpc*32 + l31
#pragma unroll
  for (int f = 0; f < 4; ++f) {
#pragma unroll
    for (int g = 0; g < 4; ++g) {
#pragma unroll
      for (int r = 0; r < 4; ++r) {
        const int o = o0 + f * 32 + r + 8 * g + 4 * half;
        const float sig  = sigma_inv[b * OUT_F + o];
        const float bias = b_conv[o];
        const int reg = g * 4 + r;
#pragma unroll
        for (int tp = 0; tp < 4; ++tp) {
          const int h = h0 + wave * 2 + (tp >> 1);
          const int w = (tp & 1) * 32 + l31;
          out[(((size_t)(b * OUT_F + o) * RES + h) * RES) + w] =
              acc[f][tp][reg] * sig + bias;
        }
      }
    }
  }
}

extern "C" void kernel_launch(void* const* d_in, const int* in_sizes, int n_in,
                              void* d_out, int out_size, void* d_ws, size_t ws_size,
                              hipStream_t stream) {
  const float* x      = (const float*)d_in[0];
  const float* latent = (const float*)d_in[1];
  const float* w_lin  = (const float*)d_in[2];
  const float* b_lin  = (const float*)d_in[3];
  const float* w_conv = (const float*)d_in[4];
  const float* b_conv = (const float*)d_in[5];
  float* out = (float*)d_out;

  char* ws = (char*)d_ws;
  char*  xmp       = ws;                            // 35,684,352 B (256 planes x 66*2*66*16)
  short* wb        = (short*)(ws + 35684352);       //  4,718,592 B
  float* w2        = (float*)(ws + 40402944);       //  1,048,576 B
  float* s         = (float*)(ws + 41451520);       //     16,384 B
  float* sigma_inv = (float*)(ws + 41467904);       //     16,384 B

  k_compute_s<<<IN_F, 64, 0, stream>>>(latent, w_lin, b_lin, s);
  k_prep_w<<<1024, 256, 0, stream>>>(w_conv, wb, w2, xmp);
  k_sigma<<<128, 256, 0, stream>>>(w2, s, sigma_inv);
  k_modulate<<<BATCH * 16 * RES, 256, 0, stream>>>(x, s, xmp);
  k_conv<<<256, 256, 0, stream>>>(xmp, wb, sigma_inv, b_conv, out);
}

// Round 3
// 258.201 us; speedup vs baseline: 1.1201x; 1.1201x over previous
//
#include <hip/hip_runtime.h>
#include <hip/hip_bf16.h>

#define IN_F 512
#define OUT_F 512
#define LATD 512
#define RES 64
#define BATCH 8
#define EPSV 1e-8f

static constexpr float C_LIN  = 0.04419417382415922f;   // 1/sqrt(512)
static constexpr float C_CONV = 0.014731391274719739f;  // 1/sqrt(512*9)

typedef __attribute__((ext_vector_type(8)))  short short8;
typedef __attribute__((ext_vector_type(16))) float f32x16;

union BF { __hip_bfloat16 h; short s; };

__device__ __forceinline__ void async_load16(const char* g, char* l) {
  __builtin_amdgcn_global_load_lds(
      (const __attribute__((address_space(1))) unsigned int*)g,
      (__attribute__((address_space(3))) unsigned int*)l, 16, 0, 0);
}

// ---------------- s = latent @ (w_lin*C).T + b_lin ----------------
__global__ void k_compute_s(const float* __restrict__ latent,
                            const float* __restrict__ w_lin,
                            const float* __restrict__ b_lin,
                            float* __restrict__ s) {
  const int i = blockIdx.x;
  const int lane = threadIdx.x;
  const float4* wl = (const float4*)(w_lin + (size_t)i * LATD);
  const float4 w0 = wl[lane * 2], w1 = wl[lane * 2 + 1];
  float acc[BATCH];
#pragma unroll
  for (int b = 0; b < BATCH; ++b) {
    const float4* lt = (const float4*)(latent + (size_t)b * LATD);
    const float4 l0 = lt[lane * 2], l1 = lt[lane * 2 + 1];
    acc[b] = w0.x * l0.x + w0.y * l0.y + w0.z * l0.z + w0.w * l0.w +
             w1.x * l1.x + w1.y * l1.y + w1.z * l1.z + w1.w * l1.w;
  }
#pragma unroll
  for (int b = 0; b < BATCH; ++b) {
    float v = acc[b];
#pragma unroll
    for (int off = 32; off > 0; off >>= 1) v += __shfl_down(v, off);
    if (lane == 0) s[b * IN_F + i] = v * C_LIN + b_lin[i];
  }
}

// ---- wb layout: [(c*4+ob)][tap][half][o128][8ch] bf16 (16B lane-stride)
// ---- w2[o][i] = sum_t w^2 ; blocks 0..255 also zero halo borders of xmp ----
__global__ void k_prep_w(const float* __restrict__ w_conv,
                         short* __restrict__ wb,
                         float* __restrict__ w2,
                         char* __restrict__ xmp) {
  const int t = blockIdx.x * 256 + threadIdx.x;   // 262144: o*512 + i
  const int o = t >> 9;
  const int i = t & 511;
  const float* src = w_conv + (size_t)t * 9;
  const int c = i >> 4, hf0 = (i >> 3) & 1, ch = i & 7;
  const int ob = o >> 7, ol = o & 127;
  short* dst = wb + (size_t)(c * 4 + ob) * 18432 + hf0 * 1024 + ol * 8 + ch;
  float sum = 0.f;
#pragma unroll
  for (int tap = 0; tap < 9; ++tap) {
    const float v = src[tap] * C_CONV;
    sum += v * v;
    BF cv; cv.h = __float2bfloat16(v);
    dst[tap * 2048] = cv.s;
  }
  w2[t] = sum;

  // fold in halo-border zeroing: plane layout [66][2][66][16B]
  if (blockIdx.x < 256) {
    char* base = xmp + (size_t)blockIdx.x * 139392;
    for (int q = threadIdx.x; q < 520; q += 256) {
      int h, hf, w;
      if (q < 132)      { h = 0;  hf = (q >= 66) ? 1 : 0; w = q - hf * 66; }
      else if (q < 264) { const int r = q - 132; h = 65; hf = (r >= 66) ? 1 : 0; w = r - hf * 66; }
      else              { const int r = q - 264; h = (r >> 2) + 1; hf = (r >> 1) & 1; w = (r & 1) * 65; }
      *(uint4*)(base + ((size_t)(h * 132 + hf * 66 + w)) * 16) = make_uint4(0u, 0u, 0u, 0u);
    }
  }
}

// ---- sigma_inv[b][o] = rsqrt(sum_i w2[o][i]*s[b][i]^2 + eps) ----
__global__ void k_sigma(const float* __restrict__ w2,
                        const float* __restrict__ s,
                        float* __restrict__ sigma_inv) {
  const int o = blockIdx.x * 4 + (threadIdx.x >> 6);
  const int lane = threadIdx.x & 63;
  float acc[BATCH];
#pragma unroll
  for (int b = 0; b < BATCH; ++b) acc[b] = 0.f;
#pragma unroll
  for (int k = 0; k < 8; ++k) {
    const int i = k * 64 + lane;
    const float w = w2[o * IN_F + i];
#pragma unroll
    for (int b = 0; b < BATCH; ++b) {
      const float sv = s[b * IN_F + i];
      acc[b] += w * sv * sv;
    }
  }
#pragma unroll
  for (int b = 0; b < BATCH; ++b) {
    float v = acc[b];
#pragma unroll
    for (int off = 32; off > 0; off >>= 1) v += __shfl_down(v, off);
    if (lane == 0) sigma_inv[b * OUT_F + o] = rsqrtf(v + EPSV);
  }
}

// ---- xmp[(c*8+b)][h+1][half][w+1][8ch] = bf16(x[b][i][h][w] * s[b][i]) ----
__global__ void k_modulate(const float* __restrict__ x,
                           const float* __restrict__ s,
                           char* __restrict__ xmp) {
  const int h    = blockIdx.x & 63;
  const int ic32 = (blockIdx.x >> 6) & 15;
  const int b    = blockIdx.x >> 10;
  __shared__ float tile[32][65];
  const int tid = threadIdx.x;
  {
    const int il = tid >> 3, w8 = (tid & 7) * 8;
    const int i = ic32 * 32 + il;
    const float sv = s[b * IN_F + i];
    const float* xp = x + (((size_t)(b * IN_F + i) * RES + h) * RES + w8);
    const float4 v0 = *(const float4*)xp;
    const float4 v1 = *(const float4*)(xp + 4);
    tile[il][w8 + 0] = v0.x * sv; tile[il][w8 + 1] = v0.y * sv;
    tile[il][w8 + 2] = v0.z * sv; tile[il][w8 + 3] = v0.w * sv;
    tile[il][w8 + 4] = v1.x * sv; tile[il][w8 + 5] = v1.y * sv;
    tile[il][w8 + 6] = v1.z * sv; tile[il][w8 + 7] = v1.w * sv;
  }
  __syncthreads();
  {
    const int w = tid >> 2, part = tid & 3;
    const int chalf = part >> 1, hf = part & 1;
    short8 pk;
#pragma unroll
    for (int j = 0; j < 8; ++j) {
      BF cv; cv.h = __float2bfloat16(tile[chalf * 16 + hf * 8 + j][w]);
      pk[j] = cv.s;
    }
    const int c = ic32 * 2 + chalf;
    char* dst = xmp + (size_t)(c * 8 + b) * 139392 +
                ((size_t)(h + 1) * 132 + hf * 66 + (w + 1)) * 16;
    *(short8*)dst = pk;
  }
}

// ---------------- main implicit-GEMM conv ----------------
// Block: 128 o x (8 rows x 64 cols) px, 8 waves (512 thr) -> 2 waves/SIMD.
// Wave = 64 o x (4 rows x 32 cols): acc[2][4] = 128 VGPR -> fits 256-cap at 2 w/EU.
// A+B both from LDS (A-from-global regressed: VMEM latency, L2 thrash).
// Per wave/chunk: 18 A + 18 B (row-dedup) ds_read_b128 = 36 KB; block 288 KB/chunk
// (~1100-2250 cyc) << MFMA 4650 cyc/CU -> MFMA-bound; 2 waves/SIMD hide stalls.
__global__ __launch_bounds__(512, 2)
void k_conv(const char* __restrict__ xmp,
            const short* __restrict__ wbg,
            const float* __restrict__ sigma_inv,
            const float* __restrict__ b_conv,
            float* __restrict__ out) {
  __shared__ __align__(16) char lds[115968];  // x: 2*21120 @0, w: 2*36864 @42240
  const int l = blockIdx.x;
  const int ob = (l >> 3) & 3;
  const int b  = l & 7;
  const int h0 = (l >> 5) * 8;
  const int o0 = ob * 128;
  const int tid = threadIdx.x;
  const int wave = tid >> 6, lane = tid & 63;
  const int l31 = lane & 31, half = lane >> 5;
  const int oh = wave >> 2;             // o-half: 0/1 -> o 0..63 / 64..127
  const int q  = wave & 3;              // px quadrant
  const int r0 = (q >> 1) * 4;          // output rows r0..r0+3
  const int c0 = (q & 1) * 32;          // output cols c0..c0+31

  f32x16 acc[2][4];
#pragma unroll
  for (int i = 0; i < 2; ++i)
#pragma unroll
    for (int j = 0; j < 4; ++j)
#pragma unroll
      for (int r = 0; r < 16; ++r) acc[i][j][r] = 0.f;

  const char* xsrc0 = xmp + (size_t)b * 139392 + (size_t)h0 * 2112;  // + ic*8*139392
  const char* wsrc0 = (const char*)wbg + (size_t)ob * 36864;         // + ic*147456

  // stage chunk 0 into parity 0 (512 threads)
#pragma unroll
  for (int k = 0; k < 2; ++k) {
    const int j = tid + k * 512;
    async_load16(xsrc0 + j * 16, lds + j * 16);
  }
  if (tid < 296) { const int j = 1024 + tid; async_load16(xsrc0 + j * 16, lds + j * 16); }
#pragma unroll
  for (int k = 0; k < 4; ++k) {
    const int j = tid + k * 512;
    async_load16(wsrc0 + j * 16, lds + 42240 + j * 16);
  }
  if (tid < 256) { const int j = 2048 + tid; async_load16(wsrc0 + j * 16, lds + 42240 + j * 16); }
  __syncthreads();

  for (int ic = 0; ic < 32; ++ic) {
    const int p = ic & 1;
    if (ic + 1 < 32) {     // prefetch next chunk into parity p^1
      const char* xs  = xsrc0 + (size_t)(ic + 1) * (8 * 139392);
      const char* wsr = wsrc0 + (size_t)(ic + 1) * 147456;
      char* xd = lds + (p ^ 1) * 21120;
      char* wd = lds + 42240 + (p ^ 1) * 36864;
#pragma unroll
      for (int k = 0; k < 2; ++k) {
        const int j = tid + k * 512;
        async_load16(xs + j * 16, xd + j * 16);
      }
      if (tid < 296) { const int j = 1024 + tid; async_load16(xs + j * 16, xd + j * 16); }
#pragma unroll
      for (int k = 0; k < 4; ++k) {
        const int j = tid + k * 512;
        async_load16(wsr + j * 16, wd + j * 16);
      }
      if (tid < 256) { const int j = 2048 + tid; async_load16(wsr + j * 16, wd + j * 16); }
    }
    const char* xp = lds + p * 21120;
    const char* wp = lds + 42240 + p * 36864;
#pragma unroll
    for (int dw = 0; dw < 3; ++dw) {
      // B rows r0..r0+5 at col offset dw (dedup'd across dh/tpr)
      short8 brow[6];
#pragma unroll
      for (int rr = 0; rr < 6; ++rr)
        brow[rr] = *(const short8*)(
            xp + (((r0 + rr) * 132) + half * 66 + c0 + dw + l31) * 16);
#pragma unroll
      for (int dh = 0; dh < 3; ++dh) {
        const int tap = dh * 3 + dw;
        short8 a[2];
#pragma unroll
        for (int f = 0; f < 2; ++f)
          a[f] = *(const short8*)(
              wp + tap * 4096 + half * 2048 + (oh * 64 + f * 32 + l31) * 16);
#pragma unroll
        for (int tpr = 0; tpr < 4; ++tpr)
#pragma unroll
          for (int f = 0; f < 2; ++f)
            acc[f][tpr] = __builtin_amdgcn_mfma_f32_32x32x16_bf16(
                a[f], brow[tpr + dh], acc[f][tpr], 0, 0, 0);
      }
    }
    __syncthreads();
  }

  // epilogue: o = o0 + oh*64 + f*32 + (reg&3) + 8*(reg>>2) + 4*half
  //           h = h0 + r0 + tpr ; w = c0 + l31
#pragma unroll
  for (int f = 0; f < 2; ++f) {
#pragma unroll
    for (int g = 0; g < 4; ++g) {
#pragma unroll
      for (int r = 0; r < 4; ++r) {
        const int o = o0 + oh * 64 + f * 32 + r + 8 * g + 4 * half;
        const float sig  = sigma_inv[b * OUT_F + o];
        const float bias = b_conv[o];
        const int reg = g * 4 + r;
#pragma unroll
        for (int tpr = 0; tpr < 4; ++tpr) {
          const int h = h0 + r0 + tpr;
          const int w = c0 + l31;
          out[(((size_t)(b * OUT_F + o) * RES + h) * RES) + w] =
              acc[f][tpr][reg] * sig + bias;
        }
      }
    }
  }
}

extern "C" void kernel_launch(void* const* d_in, const int* in_sizes, int n_in,
                              void* d_out, int out_size, void* d_ws, size_t ws_size,
                              hipStream_t stream) {
  const float* x      = (const float*)d_in[0];
  const float* latent = (const float*)d_in[1];
  const float* w_lin  = (const float*)d_in[2];
  const float* b_lin  = (const float*)d_in[3];
  const float* w_conv = (const float*)d_in[4];
  const float* b_conv = (const float*)d_in[5];
  float* out = (float*)d_out;

  char* ws = (char*)d_ws;
  char*  xmp       = ws;                            // 35,684,352 B (256 planes x 66*2*66*16)
  short* wb        = (short*)(ws + 35684352);       //  4,718,592 B
  float* w2        = (float*)(ws + 40402944);       //  1,048,576 B
  float* s         = (float*)(ws + 41451520);       //     16,384 B
  float* sigma_inv = (float*)(ws + 41467904);       //     16,384 B

  k_compute_s<<<IN_F, 64, 0, stream>>>(latent, w_lin, b_lin, s);
  k_prep_w<<<1024, 256, 0, stream>>>(w_conv, wb, w2, xmp);
  k_sigma<<<128, 256, 0, stream>>>(w2, s, sigma_inv);
  k_modulate<<<BATCH * 16 * RES, 256, 0, stream>>>(x, s, xmp);
  k_conv<<<256, 512, 0, stream>>>(xmp, wb, sigma_inv, b_conv, out);
}

// Round 4
// 248.954 us; speedup vs baseline: 1.1617x; 1.0371x over previous
//
#include <hip/hip_runtime.h>
#include <hip/hip_bf16.h>

#define IN_F 512
#define OUT_F 512
#define LATD 512
#define RES 64
#define BATCH 8
#define EPSV 1e-8f

static constexpr float C_LIN  = 0.04419417382415922f;   // 1/sqrt(512)
static constexpr float C_CONV = 0.014731391274719739f;  // 1/sqrt(512*9)

typedef __attribute__((ext_vector_type(8)))  short short8;
typedef __attribute__((ext_vector_type(16))) float f32x16;

union BF { __hip_bfloat16 h; short s; };

__device__ __forceinline__ void async_load16(const char* g, char* l) {
  __builtin_amdgcn_global_load_lds(
      (const __attribute__((address_space(1))) unsigned int*)g,
      (__attribute__((address_space(3))) unsigned int*)l, 16, 0, 0);
}

// ================= K1: prep_w (all blocks) + zero-border (<256) + compute_s (<128) ==========
// wb layout: [(c*4+ob)][tap][half][o128][8ch] bf16 ; w2[o][i] = sum_t w^2
__global__ void k_prep(const float* __restrict__ w_conv,
                       short* __restrict__ wb,
                       float* __restrict__ w2,
                       char* __restrict__ xmp,
                       const float* __restrict__ latent,
                       const float* __restrict__ w_lin,
                       const float* __restrict__ b_lin,
                       float* __restrict__ s) {
  const int t = blockIdx.x * 256 + threadIdx.x;   // 262144: o*512 + i
  {
    const int o = t >> 9;
    const int i = t & 511;
    const float* src = w_conv + (size_t)t * 9;
    const int c = i >> 4, hf0 = (i >> 3) & 1, ch = i & 7;
    const int ob = o >> 7, ol = o & 127;
    short* dst = wb + (size_t)(c * 4 + ob) * 18432 + hf0 * 1024 + ol * 8 + ch;
    float sum = 0.f;
#pragma unroll
    for (int tap = 0; tap < 9; ++tap) {
      const float v = src[tap] * C_CONV;
      sum += v * v;
      BF cv; cv.h = __float2bfloat16(v);
      dst[tap * 2048] = cv.s;
    }
    w2[t] = sum;
  }

  // halo-border zeroing: plane layout [66][2][66][16B]
  if (blockIdx.x < 256) {
    char* base = xmp + (size_t)blockIdx.x * 139392;
    for (int q = threadIdx.x; q < 520; q += 256) {
      int h, hf, w;
      if (q < 132)      { h = 0;  hf = (q >= 66) ? 1 : 0; w = q - hf * 66; }
      else if (q < 264) { const int r = q - 132; h = 65; hf = (r >= 66) ? 1 : 0; w = r - hf * 66; }
      else              { const int r = q - 264; h = (r >> 2) + 1; hf = (r >> 1) & 1; w = (r & 1) * 65; }
      *(uint4*)(base + ((size_t)(h * 132 + hf * 66 + w)) * 16) = make_uint4(0u, 0u, 0u, 0u);
    }
  }

  // s = latent @ (w_lin*C).T + b_lin : blocks 0..127, wave w -> row i = blk*4 + w
  if (blockIdx.x < 128) {
    const int wv = threadIdx.x >> 6, lane = threadIdx.x & 63;
    const int i = blockIdx.x * 4 + wv;
    const float4* wl = (const float4*)(w_lin + (size_t)i * LATD);
    const float4 w0 = wl[lane * 2], w1 = wl[lane * 2 + 1];
    float acc[BATCH];
#pragma unroll
    for (int b = 0; b < BATCH; ++b) {
      const float4* lt = (const float4*)(latent + (size_t)b * LATD);
      const float4 l0 = lt[lane * 2], l1 = lt[lane * 2 + 1];
      acc[b] = w0.x * l0.x + w0.y * l0.y + w0.z * l0.z + w0.w * l0.w +
               w1.x * l1.x + w1.y * l1.y + w1.z * l1.z + w1.w * l1.w;
    }
#pragma unroll
    for (int b = 0; b < BATCH; ++b) {
      float v = acc[b];
#pragma unroll
      for (int off = 32; off > 0; off >>= 1) v += __shfl_down(v, off);
      if (lane == 0) s[b * IN_F + i] = v * C_LIN + b_lin[i];
    }
  }
}

// ===== K2: blocks 0..127 sigma_inv ; blocks 128..8319 modulate =====
// sigma_inv[b][o] = rsqrt(sum_i w2[o][i]*s[b][i]^2 + eps)
// xmp[(c*8+b)][h+1][half][w+1][8ch] = bf16(x[b][i][h][w] * s[b][i])
__global__ void k_mod_sigma(const float* __restrict__ x,
                            const float* __restrict__ s,
                            char* __restrict__ xmp,
                            const float* __restrict__ w2,
                            float* __restrict__ sigma_inv) {
  if (blockIdx.x < 128) {
    const int o = blockIdx.x * 4 + (threadIdx.x >> 6);
    const int lane = threadIdx.x & 63;
    float acc[BATCH];
#pragma unroll
    for (int b = 0; b < BATCH; ++b) acc[b] = 0.f;
#pragma unroll
    for (int k = 0; k < 8; ++k) {
      const int i = k * 64 + lane;
      const float w = w2[o * IN_F + i];
#pragma unroll
      for (int b = 0; b < BATCH; ++b) {
        const float sv = s[b * IN_F + i];
        acc[b] += w * sv * sv;
      }
    }
#pragma unroll
    for (int b = 0; b < BATCH; ++b) {
      float v = acc[b];
#pragma unroll
      for (int off = 32; off > 0; off >>= 1) v += __shfl_down(v, off);
      if (lane == 0) sigma_inv[b * OUT_F + o] = rsqrtf(v + EPSV);
    }
    return;
  }
  const int bid  = blockIdx.x - 128;
  const int h    = bid & 63;
  const int ic32 = (bid >> 6) & 15;
  const int b    = bid >> 10;
  __shared__ float tile[32][65];
  const int tid = threadIdx.x;
  {
    const int il = tid >> 3, w8 = (tid & 7) * 8;
    const int i = ic32 * 32 + il;
    const float sv = s[b * IN_F + i];
    const float* xp = x + (((size_t)(b * IN_F + i) * RES + h) * RES + w8);
    const float4 v0 = *(const float4*)xp;
    const float4 v1 = *(const float4*)(xp + 4);
    tile[il][w8 + 0] = v0.x * sv; tile[il][w8 + 1] = v0.y * sv;
    tile[il][w8 + 2] = v0.z * sv; tile[il][w8 + 3] = v0.w * sv;
    tile[il][w8 + 4] = v1.x * sv; tile[il][w8 + 5] = v1.y * sv;
    tile[il][w8 + 6] = v1.z * sv; tile[il][w8 + 7] = v1.w * sv;
  }
  __syncthreads();
  {
    const int w = tid >> 2, part = tid & 3;
    const int chalf = part >> 1, hf = part & 1;
    short8 pk;
#pragma unroll
    for (int j = 0; j < 8; ++j) {
      BF cv; cv.h = __float2bfloat16(tile[chalf * 16 + hf * 8 + j][w]);
      pk[j] = cv.s;
    }
    const int c = ic32 * 2 + chalf;
    char* dst = xmp + (size_t)(c * 8 + b) * 139392 +
                ((size_t)(h + 1) * 132 + hf * 66 + (w + 1)) * 16;
    *(short8*)dst = pk;
  }
}

// ---------------- main implicit-GEMM conv ----------------
// Block: 128 o x (8 rows x 64 cols) px, 8 waves (512 thr) -> 2 waves/SIMD.
// Wave = 64 o x (4 rows x 32 cols): acc[2][4] = 128 VGPR (fits 256-cap @ 2 w/EU).
// A+B from LDS; B row-dedup'd (dw-major). setprio(1) around MFMA clusters (T5).
__global__ __launch_bounds__(512, 2)
void k_conv(const char* __restrict__ xmp,
            const short* __restrict__ wbg,
            const float* __restrict__ sigma_inv,
            const float* __restrict__ b_conv,
            float* __restrict__ out) {
  __shared__ __align__(16) char lds[115968];  // x: 2*21120 @0, w: 2*36864 @42240
  const int l = blockIdx.x;
  const int ob = (l >> 3) & 3;
  const int b  = l & 7;
  const int h0 = (l >> 5) * 8;
  const int o0 = ob * 128;
  const int tid = threadIdx.x;
  const int wave = tid >> 6, lane = tid & 63;
  const int l31 = lane & 31, half = lane >> 5;
  const int oh = wave >> 2;             // o-half
  const int q  = wave & 3;              // px quadrant
  const int r0 = (q >> 1) * 4;
  const int c0 = (q & 1) * 32;

  f32x16 acc[2][4];
#pragma unroll
  for (int i = 0; i < 2; ++i)
#pragma unroll
    for (int j = 0; j < 4; ++j)
#pragma unroll
      for (int r = 0; r < 16; ++r) acc[i][j][r] = 0.f;

  const char* xsrc0 = xmp + (size_t)b * 139392 + (size_t)h0 * 2112;
  const char* wsrc0 = (const char*)wbg + (size_t)ob * 36864;

  // stage chunk 0 into parity 0 (512 threads)
#pragma unroll
  for (int k = 0; k < 2; ++k) {
    const int j = tid + k * 512;
    async_load16(xsrc0 + j * 16, lds + j * 16);
  }
  if (tid < 296) { const int j = 1024 + tid; async_load16(xsrc0 + j * 16, lds + j * 16); }
#pragma unroll
  for (int k = 0; k < 4; ++k) {
    const int j = tid + k * 512;
    async_load16(wsrc0 + j * 16, lds + 42240 + j * 16);
  }
  if (tid < 256) { const int j = 2048 + tid; async_load16(wsrc0 + j * 16, lds + 42240 + j * 16); }
  __syncthreads();

  for (int ic = 0; ic < 32; ++ic) {
    const int p = ic & 1;
    if (ic + 1 < 32) {
      const char* xs  = xsrc0 + (size_t)(ic + 1) * (8 * 139392);
      const char* wsr = wsrc0 + (size_t)(ic + 1) * 147456;
      char* xd = lds + (p ^ 1) * 21120;
      char* wd = lds + 42240 + (p ^ 1) * 36864;
#pragma unroll
      for (int k = 0; k < 2; ++k) {
        const int j = tid + k * 512;
        async_load16(xs + j * 16, xd + j * 16);
      }
      if (tid < 296) { const int j = 1024 + tid; async_load16(xs + j * 16, xd + j * 16); }
#pragma unroll
      for (int k = 0; k < 4; ++k) {
        const int j = tid + k * 512;
        async_load16(wsr + j * 16, wd + j * 16);
      }
      if (tid < 256) { const int j = 2048 + tid; async_load16(wsr + j * 16, wd + j * 16); }
    }
    const char* xp = lds + p * 21120;
    const char* wp = lds + 42240 + p * 36864;
#pragma unroll
    for (int dw = 0; dw < 3; ++dw) {
      short8 brow[6];
#pragma unroll
      for (int rr = 0; rr < 6; ++rr)
        brow[rr] = *(const short8*)(
            xp + (((r0 + rr) * 132) + half * 66 + c0 + dw + l31) * 16);
#pragma unroll
      for (int dh = 0; dh < 3; ++dh) {
        const int tap = dh * 3 + dw;
        short8 a[2];
#pragma unroll
        for (int f = 0; f < 2; ++f)
          a[f] = *(const short8*)(
              wp + tap * 4096 + half * 2048 + (oh * 64 + f * 32 + l31) * 16);
        __builtin_amdgcn_s_setprio(1);
#pragma unroll
        for (int tpr = 0; tpr < 4; ++tpr)
#pragma unroll
          for (int f = 0; f < 2; ++f)
            acc[f][tpr] = __builtin_amdgcn_mfma_f32_32x32x16_bf16(
                a[f], brow[tpr + dh], acc[f][tpr], 0, 0, 0);
        __builtin_amdgcn_s_setprio(0);
      }
    }
    __syncthreads();
  }

  // epilogue: o = o0 + oh*64 + f*32 + (reg&3) + 8*(reg>>2) + 4*half
#pragma unroll
  for (int f = 0; f < 2; ++f) {
#pragma unroll
    for (int g = 0; g < 4; ++g) {
#pragma unroll
      for (int r = 0; r < 4; ++r) {
        const int o = o0 + oh * 64 + f * 32 + r + 8 * g + 4 * half;
        const float sig  = sigma_inv[b * OUT_F + o];
        const float bias = b_conv[o];
        const int reg = g * 4 + r;
#pragma unroll
        for (int tpr = 0; tpr < 4; ++tpr) {
          const int h = h0 + r0 + tpr;
          const int w = c0 + l31;
          out[(((size_t)(b * OUT_F + o) * RES + h) * RES) + w] =
              acc[f][tpr][reg] * sig + bias;
        }
      }
    }
  }
}

extern "C" void kernel_launch(void* const* d_in, const int* in_sizes, int n_in,
                              void* d_out, int out_size, void* d_ws, size_t ws_size,
                              hipStream_t stream) {
  const float* x      = (const float*)d_in[0];
  const float* latent = (const float*)d_in[1];
  const float* w_lin  = (const float*)d_in[2];
  const float* b_lin  = (const float*)d_in[3];
  const float* w_conv = (const float*)d_in[4];
  const float* b_conv = (const float*)d_in[5];
  float* out = (float*)d_out;

  char* ws = (char*)d_ws;
  char*  xmp       = ws;                            // 35,684,352 B (256 planes x 66*2*66*16)
  short* wb        = (short*)(ws + 35684352);       //  4,718,592 B
  float* w2        = (float*)(ws + 40402944);       //  1,048,576 B
  float* s         = (float*)(ws + 41451520);       //     16,384 B
  float* sigma_inv = (float*)(ws + 41467904);       //     16,384 B

  k_prep<<<1024, 256, 0, stream>>>(w_conv, wb, w2, xmp, latent, w_lin, b_lin, s);
  k_mod_sigma<<<128 + BATCH * 16 * RES, 256, 0, stream>>>(x, s, xmp, w2, sigma_inv);
  k_conv<<<256, 512, 0, stream>>>(xmp, wb, sigma_inv, b_conv, out);
}

// Round 5
// 246.705 us; speedup vs baseline: 1.1723x; 1.0091x over previous
//
#include <hip/hip_runtime.h>
#include <hip/hip_bf16.h>

#define IN_F 512
#define OUT_F 512
#define LATD 512
#define RES 64
#define BATCH 8
#define EPSV 1e-8f

static constexpr float C_LIN  = 0.04419417382415922f;   // 1/sqrt(512)
static constexpr float C_CONV = 0.014731391274719739f;  // 1/sqrt(512*9)

typedef __attribute__((ext_vector_type(8)))  short short8;
typedef __attribute__((ext_vector_type(16))) float f32x16;

union BF { __hip_bfloat16 h; short s; };

__device__ __forceinline__ void async_load16(const char* g, char* l) {
  __builtin_amdgcn_global_load_lds(
      (const __attribute__((address_space(1))) unsigned int*)g,
      (__attribute__((address_space(3))) unsigned int*)l, 16, 0, 0);
}

// ================= K1: prep_w (all blocks) + zero-border (<256) + compute_s (<128) ==========
// wb layout: [(c*4+ob)][tap][half][o128][8ch] bf16 ; w2[o][i] = sum_t w^2
__global__ void k_prep(const float* __restrict__ w_conv,
                       short* __restrict__ wb,
                       float* __restrict__ w2,
                       char* __restrict__ xmp,
                       const float* __restrict__ latent,
                       const float* __restrict__ w_lin,
                       const float* __restrict__ b_lin,
                       float* __restrict__ s) {
  const int t = blockIdx.x * 256 + threadIdx.x;   // 262144: o*512 + i
  {
    const int o = t >> 9;
    const int i = t & 511;
    const float* src = w_conv + (size_t)t * 9;
    const int c = i >> 4, hf0 = (i >> 3) & 1, ch = i & 7;
    const int ob = o >> 7, ol = o & 127;
    short* dst = wb + (size_t)(c * 4 + ob) * 18432 + hf0 * 1024 + ol * 8 + ch;
    float sum = 0.f;
#pragma unroll
    for (int tap = 0; tap < 9; ++tap) {
      const float v = src[tap] * C_CONV;
      sum += v * v;
      BF cv; cv.h = __float2bfloat16(v);
      dst[tap * 2048] = cv.s;
    }
    w2[t] = sum;
  }

  // halo-border zeroing: plane layout [66][2][66][16B]
  if (blockIdx.x < 256) {
    char* base = xmp + (size_t)blockIdx.x * 139392;
    for (int q = threadIdx.x; q < 520; q += 256) {
      int h, hf, w;
      if (q < 132)      { h = 0;  hf = (q >= 66) ? 1 : 0; w = q - hf * 66; }
      else if (q < 264) { const int r = q - 132; h = 65; hf = (r >= 66) ? 1 : 0; w = r - hf * 66; }
      else              { const int r = q - 264; h = (r >> 2) + 1; hf = (r >> 1) & 1; w = (r & 1) * 65; }
      *(uint4*)(base + ((size_t)(h * 132 + hf * 66 + w)) * 16) = make_uint4(0u, 0u, 0u, 0u);
    }
  }

  // s = latent @ (w_lin*C).T + b_lin : blocks 0..127, wave w -> row i = blk*4 + w
  if (blockIdx.x < 128) {
    const int wv = threadIdx.x >> 6, lane = threadIdx.x & 63;
    const int i = blockIdx.x * 4 + wv;
    const float4* wl = (const float4*)(w_lin + (size_t)i * LATD);
    const float4 w0 = wl[lane * 2], w1 = wl[lane * 2 + 1];
    float acc[BATCH];
#pragma unroll
    for (int b = 0; b < BATCH; ++b) {
      const float4* lt = (const float4*)(latent + (size_t)b * LATD);
      const float4 l0 = lt[lane * 2], l1 = lt[lane * 2 + 1];
      acc[b] = w0.x * l0.x + w0.y * l0.y + w0.z * l0.z + w0.w * l0.w +
               w1.x * l1.x + w1.y * l1.y + w1.z * l1.z + w1.w * l1.w;
    }
#pragma unroll
    for (int b = 0; b < BATCH; ++b) {
      float v = acc[b];
#pragma unroll
      for (int off = 32; off > 0; off >>= 1) v += __shfl_down(v, off);
      if (lane == 0) s[b * IN_F + i] = v * C_LIN + b_lin[i];
    }
  }
}

// ===== K2: blocks 0..127 sigma_inv ; blocks 128..1151 modulate (8 h-rows per block) =====
__global__ void k_mod_sigma(const float* __restrict__ x,
                            const float* __restrict__ s,
                            char* __restrict__ xmp,
                            const float* __restrict__ w2,
                            float* __restrict__ sigma_inv) {
  if (blockIdx.x < 128) {
    const int o = blockIdx.x * 4 + (threadIdx.x >> 6);
    const int lane = threadIdx.x & 63;
    float acc[BATCH];
#pragma unroll
    for (int b = 0; b < BATCH; ++b) acc[b] = 0.f;
#pragma unroll
    for (int k = 0; k < 8; ++k) {
      const int i = k * 64 + lane;
      const float w = w2[o * IN_F + i];
#pragma unroll
      for (int b = 0; b < BATCH; ++b) {
        const float sv = s[b * IN_F + i];
        acc[b] += w * sv * sv;
      }
    }
#pragma unroll
    for (int b = 0; b < BATCH; ++b) {
      float v = acc[b];
#pragma unroll
      for (int off = 32; off > 0; off >>= 1) v += __shfl_down(v, off);
      if (lane == 0) sigma_inv[b * OUT_F + o] = rsqrtf(v + EPSV);
    }
    return;
  }
  // modulate: bid -> (b, ic32, h8); each block does 8 consecutive h rows.
  const int bid  = blockIdx.x - 128;       // 0..1023
  const int h8   = bid & 7;
  const int ic32 = (bid >> 3) & 15;
  const int b    = bid >> 7;
  __shared__ float tile[32][65];
  const int tid = threadIdx.x;
  const int il = tid >> 3, w8 = (tid & 7) * 8;
  const int i  = ic32 * 32 + il;
  const float sv = s[b * IN_F + i];
  const float* xrow = x + (size_t)(b * IN_F + i) * (RES * RES) + w8;
  const int w = tid >> 2, part = tid & 3;
  const int chalf = part >> 1, hf = part & 1;
  const int c = ic32 * 2 + chalf;
  char* dstb = xmp + (size_t)(c * 8 + b) * 139392 + ((size_t)hf * 66 + (w + 1)) * 16;

  float4 v0 = *(const float4*)(xrow + (size_t)(h8 * 8) * RES);
  float4 v1 = *(const float4*)(xrow + (size_t)(h8 * 8) * RES + 4);
#pragma unroll
  for (int hh = 0; hh < 8; ++hh) {
    const int h = h8 * 8 + hh;
    tile[il][w8 + 0] = v0.x * sv; tile[il][w8 + 1] = v0.y * sv;
    tile[il][w8 + 2] = v0.z * sv; tile[il][w8 + 3] = v0.w * sv;
    tile[il][w8 + 4] = v1.x * sv; tile[il][w8 + 5] = v1.y * sv;
    tile[il][w8 + 6] = v1.z * sv; tile[il][w8 + 7] = v1.w * sv;
    float4 n0, n1;
    if (hh < 7) {        // issue next row's load before the barriers
      n0 = *(const float4*)(xrow + (size_t)(h + 1) * RES);
      n1 = *(const float4*)(xrow + (size_t)(h + 1) * RES + 4);
    }
    __syncthreads();
    short8 pk;
#pragma unroll
    for (int j = 0; j < 8; ++j) {
      BF cv; cv.h = __float2bfloat16(tile[chalf * 16 + hf * 8 + j][w]);
      pk[j] = cv.s;
    }
    *(short8*)(dstb + (size_t)(h + 1) * 2112) = pk;
    __syncthreads();
    v0 = n0; v1 = n1;
  }
}

// ---------------- main implicit-GEMM conv ----------------
// Block: 128 o x (8 rows x 64 cols) px, 8 waves (512 thr) -> 2 waves/SIMD.
// Wave = 64 o x (4 rows x 32 cols): acc[2][4] = 128 AGPR.
// NEW: dw-phase staggered by (wave>>2)&1 so each SIMD's two waves are one
// phase apart (role diversity -> setprio pays, read bursts anti-align);
// A-fragment reads software-pipelined one dh-step ahead.
__global__ __launch_bounds__(512, 2)
void k_conv(const char* __restrict__ xmp,
            const short* __restrict__ wbg,
            const float* __restrict__ sigma_inv,
            const float* __restrict__ b_conv,
            float* __restrict__ out) {
  __shared__ __align__(16) char lds[115968];  // x: 2*21120 @0, w: 2*36864 @42240
  const int l = blockIdx.x;
  const int ob = (l >> 3) & 3;
  const int b  = l & 7;
  const int h0 = (l >> 5) * 8;
  const int o0 = ob * 128;
  const int tid = threadIdx.x;
  const int wave = tid >> 6, lane = tid & 63;
  const int l31 = lane & 31, half = lane >> 5;
  const int oh = wave >> 2;             // o-half
  const int q  = wave & 3;              // px quadrant
  const int r0 = (q >> 1) * 4;
  const int c0 = (q & 1) * 32;
  const int st = (wave >> 2) & 1;       // dw-phase stagger (pairs SIMD-sharing waves)
  const int dseq[3] = {st, st + 1, st ? 0 : 2};

  f32x16 acc[2][4];
#pragma unroll
  for (int i = 0; i < 2; ++i)
#pragma unroll
    for (int j = 0; j < 4; ++j)
#pragma unroll
      for (int r = 0; r < 16; ++r) acc[i][j][r] = 0.f;

  const char* xsrc0 = xmp + (size_t)b * 139392 + (size_t)h0 * 2112;
  const char* wsrc0 = (const char*)wbg + (size_t)ob * 36864;

  // stage chunk 0 into parity 0 (512 threads)
#pragma unroll
  for (int k = 0; k < 2; ++k) {
    const int j = tid + k * 512;
    async_load16(xsrc0 + j * 16, lds + j * 16);
  }
  if (tid < 296) { const int j = 1024 + tid; async_load16(xsrc0 + j * 16, lds + j * 16); }
#pragma unroll
  for (int k = 0; k < 4; ++k) {
    const int j = tid + k * 512;
    async_load16(wsrc0 + j * 16, lds + 42240 + j * 16);
  }
  if (tid < 256) { const int j = 2048 + tid; async_load16(wsrc0 + j * 16, lds + 42240 + j * 16); }
  __syncthreads();

  for (int ic = 0; ic < 32; ++ic) {
    const int p = ic & 1;
    if (ic + 1 < 32) {
      const char* xs  = xsrc0 + (size_t)(ic + 1) * (8 * 139392);
      const char* wsr = wsrc0 + (size_t)(ic + 1) * 147456;
      char* xd = lds + (p ^ 1) * 21120;
      char* wd = lds + 42240 + (p ^ 1) * 36864;
#pragma unroll
      for (int k = 0; k < 2; ++k) {
        const int j = tid + k * 512;
        async_load16(xs + j * 16, xd + j * 16);
      }
      if (tid < 296) { const int j = 1024 + tid; async_load16(xs + j * 16, xd + j * 16); }
#pragma unroll
      for (int k = 0; k < 4; ++k) {
        const int j = tid + k * 512;
        async_load16(wsr + j * 16, wd + j * 16);
      }
      if (tid < 256) { const int j = 2048 + tid; async_load16(wsr + j * 16, wd + j * 16); }
    }
    const char* xp = lds + p * 21120;
    const char* wp = lds + 42240 + p * 36864;

    // A software pipeline: a_cur for first (dw,dh); prefetch next inside loop
    short8 a_cur[2], a_nxt[2];
#pragma unroll
    for (int f = 0; f < 2; ++f)
      a_cur[f] = *(const short8*)(
          wp + dseq[0] * 4096 + half * 2048 + (oh * 64 + f * 32 + l31) * 16);

#pragma unroll
    for (int dwi = 0; dwi < 3; ++dwi) {
      const int dw = dseq[dwi];
      short8 brow[6];
#pragma unroll
      for (int rr = 0; rr < 6; ++rr)
        brow[rr] = *(const short8*)(
            xp + (((r0 + rr) * 132) + half * 66 + c0 + dw + l31) * 16);
#pragma unroll
      for (int dh = 0; dh < 3; ++dh) {
        if (!(dwi == 2 && dh == 2)) {
          const int dh_n = (dh < 2) ? dh + 1 : 0;
          const int dw_n = (dh < 2) ? dw : dseq[dwi + 1];
#pragma unroll
          for (int f = 0; f < 2; ++f)
            a_nxt[f] = *(const short8*)(
                wp + (dh_n * 3 + dw_n) * 4096 + half * 2048 + (oh * 64 + f * 32 + l31) * 16);
        }
        __builtin_amdgcn_s_setprio(1);
#pragma unroll
        for (int tpr = 0; tpr < 4; ++tpr)
#pragma unroll
          for (int f = 0; f < 2; ++f)
            acc[f][tpr] = __builtin_amdgcn_mfma_f32_32x32x16_bf16(
                a_cur[f], brow[tpr + dh], acc[f][tpr], 0, 0, 0);
        __builtin_amdgcn_s_setprio(0);
        a_cur[0] = a_nxt[0]; a_cur[1] = a_nxt[1];
      }
    }
    __syncthreads();
  }

  // epilogue: o = o0 + oh*64 + f*32 + (reg&3) + 8*(reg>>2) + 4*half
#pragma unroll
  for (int f = 0; f < 2; ++f) {
#pragma unroll
    for (int g = 0; g < 4; ++g) {
#pragma unroll
      for (int r = 0; r < 4; ++r) {
        const int o = o0 + oh * 64 + f * 32 + r + 8 * g + 4 * half;
        const float sig  = sigma_inv[b * OUT_F + o];
        const float bias = b_conv[o];
        const int reg = g * 4 + r;
#pragma unroll
        for (int tpr = 0; tpr < 4; ++tpr) {
          const int h = h0 + r0 + tpr;
          const int w = c0 + l31;
          out[(((size_t)(b * OUT_F + o) * RES + h) * RES) + w] =
              acc[f][tpr][reg] * sig + bias;
        }
      }
    }
  }
}

extern "C" void kernel_launch(void* const* d_in, const int* in_sizes, int n_in,
                              void* d_out, int out_size, void* d_ws, size_t ws_size,
                              hipStream_t stream) {
  const float* x      = (const float*)d_in[0];
  const float* latent = (const float*)d_in[1];
  const float* w_lin  = (const float*)d_in[2];
  const float* b_lin  = (const float*)d_in[3];
  const float* w_conv = (const float*)d_in[4];
  const float* b_conv = (const float*)d_in[5];
  float* out = (float*)d_out;

  char* ws = (char*)d_ws;
  char*  xmp       = ws;                            // 35,684,352 B (256 planes x 66*2*66*16)
  short* wb        = (short*)(ws + 35684352);       //  4,718,592 B
  float* w2        = (float*)(ws + 40402944);       //  1,048,576 B
  float* s         = (float*)(ws + 41451520);       //     16,384 B
  float* sigma_inv = (float*)(ws + 41467904);       //     16,384 B

  k_prep<<<1024, 256, 0, stream>>>(w_conv, wb, w2, xmp, latent, w_lin, b_lin, s);
  k_mod_sigma<<<128 + 1024, 256, 0, stream>>>(x, s, xmp, w2, sigma_inv);
  k_conv<<<256, 512, 0, stream>>>(xmp, wb, sigma_inv, b_conv, out);
}